// Round 3
// baseline (1825.062 us; speedup 1.0000x reference)
//
#include <hip/hip_runtime.h>

#define EMBED 1024
#define MLP   2048
#define NE    8
#define NTOK  8192                      // 4*2048 tokens
#define RMAX  (2*NTOK + NE*256)         // 18432 rows max (256-pad per expert)

typedef _Float16 f16x8 __attribute__((ext_vector_type(8)));
typedef _Float16 f16x4 __attribute__((ext_vector_type(4)));
typedef float    f32x4 __attribute__((ext_vector_type(4)));

// Async 16B global->LDS copy. LDS dest is wave-uniform base + lane*16 (HW
// constraint); we permute WHICH global chunk each lane fetches (XOR swizzle).
__device__ __forceinline__ void async_copy16(const void* g, void* l) {
  __builtin_amdgcn_global_load_lds(
      (const __attribute__((address_space(1))) unsigned int*)g,
      (__attribute__((address_space(3))) unsigned int*)l, 16, 0, 0);
}

// ---------------------------------------------------------------------------
// Router: one wave per token. logits = x[t] @ gate_w (fp32), top-2, weights =
// softmax over the two selected logits (== renormalized full softmax).
// ---------------------------------------------------------------------------
__global__ __launch_bounds__(256) void router_kernel(
    const float* __restrict__ x, const float* __restrict__ gw,
    int* __restrict__ sel_e, float* __restrict__ sel_w, int* __restrict__ counts)
{
  __shared__ float gwt[NE * EMBED];   // transposed gate: gwt[e][i]
  __shared__ int cnt[NE];
  int tid = threadIdx.x;
  for (int idx = tid; idx < NE * EMBED; idx += 256) {
    int i = idx >> 3, e = idx & 7;
    gwt[e * EMBED + i] = gw[idx];     // gw is [EMBED][NE]
  }
  if (tid < NE) cnt[tid] = 0;
  __syncthreads();

  int lane = tid & 63, wv = tid >> 6;
  int t = blockIdx.x * 4 + wv;
  const float4* xr = (const float4*)(x + (size_t)t * EMBED);
  const float4* gt4 = (const float4*)gwt;
  float acc[NE];
  #pragma unroll
  for (int e = 0; e < NE; ++e) acc[e] = 0.f;
  #pragma unroll
  for (int c = 0; c < 4; ++c) {
    float4 xv = xr[c * 64 + lane];
    #pragma unroll
    for (int e = 0; e < NE; ++e) {
      float4 gv = gt4[e * 256 + c * 64 + lane];
      acc[e] += xv.x * gv.x + xv.y * gv.y + xv.z * gv.z + xv.w * gv.w;
    }
  }
  #pragma unroll
  for (int off = 1; off < 64; off <<= 1) {
    #pragma unroll
    for (int e = 0; e < NE; ++e) acc[e] += __shfl_xor(acc[e], off);
  }
  if (lane == 0) {
    int e0 = 0; float l0 = acc[0];
    #pragma unroll
    for (int e = 1; e < NE; ++e) if (acc[e] > l0) { l0 = acc[e]; e0 = e; }
    int e1 = -1; float l1 = -1e30f;
    #pragma unroll
    for (int e = 0; e < NE; ++e) if (e != e0 && acc[e] > l1) { l1 = acc[e]; e1 = e; }
    float w0 = 1.f / (1.f + expf(l1 - l0));   // softmax over {l0,l1}
    sel_e[2 * t] = e0;     sel_w[2 * t] = w0;
    sel_e[2 * t + 1] = e1; sel_w[2 * t + 1] = 1.f - w0;
    atomicAdd(&cnt[e0], 1); atomicAdd(&cnt[e1], 1);
  }
  __syncthreads();
  if (tid < NE && cnt[tid]) atomicAdd(&counts[tid], cnt[tid]);
}

// ---------------------------------------------------------------------------
// Assign: scatter (token, weight) into per-expert row lists + inverse map.
// Segment starts are 256-aligned (so a 256-row GEMM tile never straddles
// experts). Block 0 publishes offs; cursor is zero-based per segment.
// ---------------------------------------------------------------------------
__global__ __launch_bounds__(256) void assign_kernel(
    const int* __restrict__ sel_e, const float* __restrict__ sel_w,
    const int* __restrict__ counts, int* __restrict__ cursor,
    int* __restrict__ offs_out, int* __restrict__ rowtok,
    float* __restrict__ rowcoef, int* __restrict__ inv)
{
  int offl[NE];
  {
    int o = 0;
    #pragma unroll
    for (int e = 0; e < NE; ++e) { offl[e] = o; o += (counts[e] + 255) & ~255; }
    if (blockIdx.x == 0 && threadIdx.x == 0) {
      #pragma unroll
      for (int e = 0; e < NE; ++e) offs_out[e] = offl[e];
      offs_out[NE] = o;
    }
  }
  int t = blockIdx.x * 256 + threadIdx.x;
  int lane = threadIdx.x & 63;
  #pragma unroll
  for (int k = 0; k < 2; ++k) {
    int e = sel_e[2 * t + k];
    float w = sel_w[2 * t + k];
    for (int xch = 0; xch < NE; ++xch) {
      unsigned long long m = __ballot(e == xch);
      if (e == xch) {
        int leader = __ffsll((unsigned long long)m) - 1;
        int base = 0;
        if (lane == leader) base = atomicAdd(&cursor[xch], (int)__popcll(m));
        base = __shfl(base, leader);
        int pos = offl[xch] + base + (int)__popcll(m & ((1ull << lane) - 1));
        rowtok[pos] = t;
        rowcoef[pos] = w;
        inv[2 * t + k] = pos;
      }
    }
  }
}

// ---------------------------------------------------------------------------
// Gather: xg[row] = fp16(x[rowtok[row]]); zeros for padding rows (tok = -1).
// ---------------------------------------------------------------------------
__global__ __launch_bounds__(256) void gather_kernel(
    const float* __restrict__ x, const int* __restrict__ rowtok,
    _Float16* __restrict__ xg)
{
  int r = blockIdx.x;
  int tok = rowtok[r];
  int t4 = threadIdx.x * 4;
  _Float16* dst = xg + (size_t)r * EMBED + t4;
  if (tok >= 0) {
    float4 v = *(const float4*)(x + (size_t)tok * EMBED + t4);
    f16x4 h; h.x = (_Float16)v.x; h.y = (_Float16)v.y; h.z = (_Float16)v.z; h.w = (_Float16)v.w;
    *(f16x4*)dst = h;
  } else {
    f16x4 z = {(_Float16)0.f, (_Float16)0.f, (_Float16)0.f, (_Float16)0.f};
    *(f16x4*)dst = z;
  }
}

// ---------------------------------------------------------------------------
// Transpose+cast all three weight tensors in ONE launch.
// fp32 [E][K][N] -> fp16 [E][N][K]. 512 64x64 tiles per (matrix, expert).
// ---------------------------------------------------------------------------
__global__ __launch_bounds__(256) void transpose_all_kernel(
    const float* __restrict__ w1, const float* __restrict__ w3,
    const float* __restrict__ w2, _Float16* __restrict__ w1t,
    _Float16* __restrict__ w3t, _Float16* __restrict__ w2t)
{
  int id = blockIdx.x;            // 3 * 8 * 512
  int mat = id >> 12;             // 4096 blocks per matrix
  int rr = id & 4095;
  int e = rr >> 9, tile = rr & 511;
  const float* src; _Float16* dst; int K, N;
  if (mat == 0)      { src = w1; dst = w1t; K = EMBED; N = MLP; }
  else if (mat == 1) { src = w3; dst = w3t; K = EMBED; N = MLP; }
  else               { src = w2; dst = w2t; K = MLP;   N = EMBED; }
  int nx = K >> 6;
  int k0 = (tile % nx) * 64, n0 = (tile / nx) * 64;
  src += (size_t)e * K * N;
  dst += (size_t)e * K * N;

  __shared__ float tilebuf[64][65];
  int t = threadIdx.x;
  int r = t >> 4, c4 = (t & 15) * 4;
  #pragma unroll
  for (int i = 0; i < 4; ++i) {
    float4 v = *(const float4*)(src + (size_t)(k0 + r + 16 * i) * N + n0 + c4);
    tilebuf[r + 16 * i][c4 + 0] = v.x;
    tilebuf[r + 16 * i][c4 + 1] = v.y;
    tilebuf[r + 16 * i][c4 + 2] = v.z;
    tilebuf[r + 16 * i][c4 + 3] = v.w;
  }
  __syncthreads();
  int kk8 = (t & 7) * 8, nIdx = t >> 3;
  #pragma unroll
  for (int i = 0; i < 2; ++i) {
    int n = nIdx + 32 * i;
    f16x8 h;
    #pragma unroll
    for (int j = 0; j < 8; ++j) h[j] = (_Float16)tilebuf[kk8 + j][n];
    *(f16x8*)(dst + (size_t)(n0 + n) * K + k0 + kk8) = h;
  }
}

// ---------------------------------------------------------------------------
__device__ __forceinline__ int resolve_expert(const int* __restrict__ offs, int r0)
{
  int e = 0;
  #pragma unroll
  for (int q = 0; q < NE - 1; ++q) if (r0 >= offs[q + 1]) e = q + 1;
  return e;
}

// Tile rows x 32 f16 (64 B/row), 4 chunks of 16 B per row.
// Physical slot (row, kqp) holds logical k-quarter kql = kqp ^ ((row>>1)&3)
// (round-2-verified: 0 bank conflicts). Read: phys = quad ^ ((row>>1)&3).
__device__ __forceinline__ const _Float16* frag_addr(const _Float16* buf, int row, int quad)
{
  return buf + row * 32 + ((quad ^ ((row >> 1) & 3)) << 3);
}

// XCD-chunked bijective block swizzle (grid.x must be 72, nwg % 8 == 0).
// XCD k owns x-tiles [9k, 9k+9); within a chunk x varies fastest so the
// 9 A-tiles + current B-panel stay resident in that XCD's L2.
__device__ __forceinline__ void swz_block(int& x, int& y)
{
  int lin = blockIdx.y * 72 + blockIdx.x;   // dispatch index (x fastest)
  int xcd = lin & 7, idx = lin >> 3;
  x = xcd * 9 + idx % 9;
  y = idx / 9;
}

// ---------------------------------------------------------------------------
// GEMM1 (fused SwiGLU): h = silu(xg@w1t^T) * (xg@w3t^T) * coef, fp16 out.
// 256x128 tile, 512 threads / 8 waves (wave tile 64x64), BK=32.
// DOUBLE-buffered LDS (64 KB -> 2 blocks/CU), 2 barriers per K-iter:
//   barrier1 after counted vmcnt  -> staged buf b visible to all waves
//   barrier2 after lgkmcnt(0)     -> all frag reads of buf b retired, so the
//                                    next iter may stage into buf b^1 safely
// Counted vmcnt(4) keeps stage(k+1) in flight across both barriers.
// ---------------------------------------------------------------------------
__global__ __launch_bounds__(512, 4) void gemm1_kernel(
    const _Float16* __restrict__ xg, const _Float16* __restrict__ w1t,
    const _Float16* __restrict__ w3t, const float* __restrict__ rowcoef,
    const int* __restrict__ offs, _Float16* __restrict__ hb)
{
  int bx, by; swz_block(bx, by);
  int r0 = bx * 256;
  if (r0 >= offs[NE]) return;
  int e = resolve_expert(offs, r0);
  int n0 = by * 128;
  const _Float16* B1 = w1t + (size_t)e * MLP * EMBED;
  const _Float16* B3 = w3t + (size_t)e * MLP * EMBED;

  __shared__ __align__(16) _Float16 As[2][256 * 32];    // 2 x 16 KB
  __shared__ __align__(16) _Float16 Bs1[2][128 * 32];   // 2 x 8 KB
  __shared__ __align__(16) _Float16 Bs3[2][128 * 32];   // 2 x 8 KB

  int tid = threadIdx.x, lane = tid & 63, wv = tid >> 6;  // wv 0..7
  int wm = (wv & 3) << 6, wn = (wv >> 2) << 6;            // 4 m-waves x 2 n-waves
  int l16 = lane & 15, quad = lane >> 4;

  // A: 1024 chunks, 2 per thread (c = tid, tid+512). B: 512 chunks, 1/thread.
  int rowA0 = tid >> 2, kqpA = tid & 3;
  int rowA1 = rowA0 + 128;
  int kqlA0 = kqpA ^ ((rowA0 >> 1) & 3);
  int kqlA1 = kqpA ^ ((rowA1 >> 1) & 3);
  int rowB = tid >> 2, kqpB = tid & 3;
  int kqlB = kqpB ^ ((rowB >> 1) & 3);
  size_t gA0 = (size_t)(r0 + rowA0) * EMBED + kqlA0 * 8;
  size_t gA1 = (size_t)(r0 + rowA1) * EMBED + kqlA1 * 8;
  size_t gB  = (size_t)(n0 + rowB) * EMBED + kqlB * 8;
  int lofA0 = (wv * 64) * 8;          // wave-uniform LDS bases (f16 units)
  int lofA1 = (512 + wv * 64) * 8;
  int lofB  = (wv * 64) * 8;

  f32x4 acc1[4][4], acc3[4][4];
  f32x4 z4 = {0.f, 0.f, 0.f, 0.f};
  #pragma unroll
  for (int i = 0; i < 4; ++i)
    #pragma unroll
    for (int j = 0; j < 4; ++j) { acc1[i][j] = z4; acc3[i][j] = z4; }

  auto stage = [&](int b, int kk) {
    async_copy16(xg + gA0 + kk, &As[b][lofA0]);
    async_copy16(xg + gA1 + kk, &As[b][lofA1]);
    async_copy16(B1 + gB  + kk, &Bs1[b][lofB]);
    async_copy16(B3 + gB  + kk, &Bs3[b][lofB]);
  };

  const int NIT = EMBED / 32;        // 32 iters
  stage(0, 0);
  int b = 0;
  for (int k = 0; k < NIT; ++k) {
    if (k + 1 < NIT) {
      stage(b ^ 1, (k + 1) * 32);
      asm volatile("s_waitcnt vmcnt(4)" ::: "memory");   // stage(k) drained
    } else {
      asm volatile("s_waitcnt vmcnt(0)" ::: "memory");
    }
    asm volatile("s_barrier" ::: "memory");              // buf b ready

    f16x8 af[4], b1f[4], b3f[4];
    #pragma unroll
    for (int i = 0; i < 4; ++i)
      af[i] = *(const f16x8*)frag_addr(As[b], wm + 16 * i + l16, quad);
    #pragma unroll
    for (int j = 0; j < 4; ++j) {
      b1f[j] = *(const f16x8*)frag_addr(Bs1[b], wn + 16 * j + l16, quad);
      b3f[j] = *(const f16x8*)frag_addr(Bs3[b], wn + 16 * j + l16, quad);
    }
    asm volatile("s_waitcnt lgkmcnt(0)" ::: "memory");   // frag reads retired
    asm volatile("s_barrier" ::: "memory");              // buf b free for restage

    #pragma unroll
    for (int i = 0; i < 4; ++i)
      #pragma unroll
      for (int j = 0; j < 4; ++j) {
        acc1[i][j] = __builtin_amdgcn_mfma_f32_16x16x32_f16(af[i], b1f[j], acc1[i][j], 0, 0, 0);
        acc3[i][j] = __builtin_amdgcn_mfma_f32_16x16x32_f16(af[i], b3f[j], acc3[i][j], 0, 0, 0);
      }
    b ^= 1;
  }

  // Epilogue: h = silu(g)*u*coef[row]; C/D layout col=lane&15, row=quad*4+reg.
  #pragma unroll
  for (int i = 0; i < 4; ++i) {
    int mb = r0 + wm + 16 * i + quad * 4;
    float cf[4];
    #pragma unroll
    for (int rg = 0; rg < 4; ++rg) cf[rg] = rowcoef[mb + rg];
    #pragma unroll
    for (int j = 0; j < 4; ++j) {
      int col = n0 + wn + 16 * j + l16;
      #pragma unroll
      for (int rg = 0; rg < 4; ++rg) {
        float g = acc1[i][j][rg], u = acc3[i][j][rg];
        float h = g * u * cf[rg] / (1.f + __expf(-g));
        hb[(size_t)(mb + rg) * MLP + col] = (_Float16)h;
      }
    }
  }
}

// ---------------------------------------------------------------------------
// GEMM2: hb2[row] = h[row] @ w2t^T, fp16 per-row out (no atomics; combine
// sums the 2 rows per token). 256x128 tile, same 2-barrier double-buffer,
// K=2048. LDS 48 KB -> 2 blocks/CU (VGPR-capped).
// ---------------------------------------------------------------------------
__global__ __launch_bounds__(512, 4) void gemm2_kernel(
    const _Float16* __restrict__ hb, const _Float16* __restrict__ w2t,
    const int* __restrict__ offs, _Float16* __restrict__ hb2)
{
  int bx, by; swz_block(bx, by);
  int r0 = bx * 256;
  if (r0 >= offs[NE]) return;
  int e = resolve_expert(offs, r0);
  int n0 = by * 128;
  const _Float16* B = w2t + (size_t)e * EMBED * MLP;

  __shared__ __align__(16) _Float16 As[2][256 * 32];    // 2 x 16 KB
  __shared__ __align__(16) _Float16 Bs[2][128 * 32];    // 2 x 8 KB

  int tid = threadIdx.x, lane = tid & 63, wv = tid >> 6;
  int wm = (wv & 3) << 6, wn = (wv >> 2) << 6;
  int l16 = lane & 15, quad = lane >> 4;

  int rowA0 = tid >> 2, kqpA = tid & 3;
  int rowA1 = rowA0 + 128;
  int kqlA0 = kqpA ^ ((rowA0 >> 1) & 3);
  int kqlA1 = kqpA ^ ((rowA1 >> 1) & 3);
  int rowB = tid >> 2, kqpB = tid & 3;
  int kqlB = kqpB ^ ((rowB >> 1) & 3);
  size_t gA0 = (size_t)(r0 + rowA0) * MLP + kqlA0 * 8;
  size_t gA1 = (size_t)(r0 + rowA1) * MLP + kqlA1 * 8;
  size_t gB  = (size_t)(n0 + rowB) * MLP + kqlB * 8;
  int lofA0 = (wv * 64) * 8;
  int lofA1 = (512 + wv * 64) * 8;
  int lofB  = (wv * 64) * 8;

  f32x4 acc[4][4];
  f32x4 z4 = {0.f, 0.f, 0.f, 0.f};
  #pragma unroll
  for (int i = 0; i < 4; ++i)
    #pragma unroll
    for (int j = 0; j < 4; ++j) acc[i][j] = z4;

  auto stage = [&](int b, int kk) {
    async_copy16(hb + gA0 + kk, &As[b][lofA0]);
    async_copy16(hb + gA1 + kk, &As[b][lofA1]);
    async_copy16(B  + gB  + kk, &Bs[b][lofB]);
  };

  const int NIT = MLP / 32;          // 64 iters
  stage(0, 0);
  int b = 0;
  for (int k = 0; k < NIT; ++k) {
    if (k + 1 < NIT) {
      stage(b ^ 1, (k + 1) * 32);
      asm volatile("s_waitcnt vmcnt(3)" ::: "memory");
    } else {
      asm volatile("s_waitcnt vmcnt(0)" ::: "memory");
    }
    asm volatile("s_barrier" ::: "memory");

    f16x8 af[4], bf[4];
    #pragma unroll
    for (int i = 0; i < 4; ++i)
      af[i] = *(const f16x8*)frag_addr(As[b], wm + 16 * i + l16, quad);
    #pragma unroll
    for (int j = 0; j < 4; ++j)
      bf[j] = *(const f16x8*)frag_addr(Bs[b], wn + 16 * j + l16, quad);
    asm volatile("s_waitcnt lgkmcnt(0)" ::: "memory");
    asm volatile("s_barrier" ::: "memory");

    #pragma unroll
    for (int i = 0; i < 4; ++i)
      #pragma unroll
      for (int j = 0; j < 4; ++j)
        acc[i][j] = __builtin_amdgcn_mfma_f32_16x16x32_f16(af[i], bf[j], acc[i][j], 0, 0, 0);
    b ^= 1;
  }

  #pragma unroll
  for (int i = 0; i < 4; ++i) {
    int mb = r0 + wm + 16 * i + quad * 4;
    #pragma unroll
    for (int j = 0; j < 4; ++j) {
      int col = n0 + wn + 16 * j + l16;
      #pragma unroll
      for (int rg = 0; rg < 4; ++rg)
        hb2[(size_t)(mb + rg) * EMBED + col] = (_Float16)acc[i][j][rg];
    }
  }
}

// ---------------------------------------------------------------------------
// Combine: out[t] = hb2[inv[2t]] + hb2[inv[2t+1]] (fp32 out).
// ---------------------------------------------------------------------------
__global__ __launch_bounds__(256) void combine_kernel(
    const _Float16* __restrict__ hb2, const int* __restrict__ inv,
    float* __restrict__ out)
{
  int t = blockIdx.x;
  int d = threadIdx.x * 4;
  int p0 = inv[2 * t], p1 = inv[2 * t + 1];
  f16x4 a = *(const f16x4*)(hb2 + (size_t)p0 * EMBED + d);
  f16x4 b = *(const f16x4*)(hb2 + (size_t)p1 * EMBED + d);
  float4 r;
  r.x = (float)a.x + (float)b.x;
  r.y = (float)a.y + (float)b.y;
  r.z = (float)a.z + (float)b.z;
  r.w = (float)a.w + (float)b.w;
  *(float4*)(out + (size_t)t * EMBED + d) = r;
}

// ---------------------------------------------------------------------------
extern "C" void kernel_launch(void* const* d_in, const int* in_sizes, int n_in,
                              void* d_out, int out_size, void* d_ws, size_t ws_size,
                              hipStream_t stream)
{
  (void)in_sizes; (void)n_in; (void)ws_size; (void)out_size;
  const float* x  = (const float*)d_in[0];
  const float* gw = (const float*)d_in[1];
  const float* w1 = (const float*)d_in[2];
  const float* w2 = (const float*)d_in[3];   // NOTE: dict order is w1, w2, w3
  const float* w3 = (const float*)d_in[4];
  float* out = (float*)d_out;
  char* ws = (char*)d_ws;

  size_t o = 0;
  auto alloc = [&](size_t bytes) { size_t r = o; o = (o + bytes + 255) & ~255ULL; return r; };
  const size_t wbytes = (size_t)NE * MLP * EMBED * 2;
  _Float16* w1t = (_Float16*)(ws + alloc(wbytes));
  _Float16* w3t = (_Float16*)(ws + alloc(wbytes));
  _Float16* w2t = (_Float16*)(ws + alloc(wbytes));
  _Float16* xg  = (_Float16*)(ws + alloc((size_t)RMAX * EMBED * 2));
  _Float16* hb  = (_Float16*)(ws + alloc((size_t)RMAX * MLP * 2));
  int*   rowtok  = (int*)(ws + alloc((size_t)RMAX * 4));
  float* rowcoef = (float*)(ws + alloc((size_t)RMAX * 4));
  int*   sel_e   = (int*)(ws + alloc((size_t)2 * NTOK * 4));
  float* sel_w   = (float*)(ws + alloc((size_t)2 * NTOK * 4));
  int*   inv     = (int*)(ws + alloc((size_t)2 * NTOK * 4));
  int*   meta    = (int*)(ws + alloc(256));
  int* counts = meta;          // [8]
  int* offs   = meta + 8;      // [9]
  int* cursor = meta + 17;     // [8] (zero-based)
  // hb2 aliases xg: xg is dead after gemm1; both are RMAX*EMBED fp16.
  _Float16* hb2 = xg;

  hipMemsetAsync(meta, 0, 256, stream);
  hipMemsetAsync(rowtok, 0xFF, (size_t)RMAX * 4, stream);   // -1 = padding
  hipMemsetAsync(rowcoef, 0, (size_t)RMAX * 4, stream);

  transpose_all_kernel<<<3 * 4096, 256, 0, stream>>>(w1, w3, w2, w1t, w3t, w2t);

  router_kernel<<<NTOK / 4, 256, 0, stream>>>(x, gw, sel_e, sel_w, counts);
  assign_kernel<<<NTOK / 256, 256, 0, stream>>>(sel_e, sel_w, counts, cursor,
                                                offs, rowtok, rowcoef, inv);
  gather_kernel<<<RMAX, 256, 0, stream>>>(x, rowtok, xg);

  gemm1_kernel<<<dim3(RMAX / 256, MLP / 128), 512, 0, stream>>>(xg, w1t, w3t, rowcoef, offs, hb);
  gemm2_kernel<<<dim3(RMAX / 256, EMBED / 128), 512, 0, stream>>>(hb, w2t, offs, hb2);
  combine_kernel<<<NTOK, 256, 0, stream>>>(hb2, inv, out);
}

// Round 4
// 642.448 us; speedup vs baseline: 2.8408x; 2.8408x over previous
//
#include <hip/hip_runtime.h>

#define EMBED 1024
#define MLP   2048
#define NE    8
#define NTOK  8192                      // 4*2048 tokens
#define RMAX  (2*NTOK + NE*256)         // 18432 rows max (256-pad per expert)

typedef _Float16 f16x8 __attribute__((ext_vector_type(8)));
typedef _Float16 f16x4 __attribute__((ext_vector_type(4)));
typedef float    f32x4 __attribute__((ext_vector_type(4)));

// Async 16B global->LDS copy. LDS dest is wave-uniform base + lane*16 (HW
// constraint); we permute WHICH global chunk each lane fetches (XOR swizzle).
__device__ __forceinline__ void async_copy16(const void* g, void* l) {
  __builtin_amdgcn_global_load_lds(
      (const __attribute__((address_space(1))) unsigned int*)g,
      (__attribute__((address_space(3))) unsigned int*)l, 16, 0, 0);
}

// ---------------------------------------------------------------------------
// Router: one wave per token. logits = x[t] @ gate_w (fp32), top-2, weights =
// softmax over the two selected logits (== renormalized full softmax).
// ---------------------------------------------------------------------------
__global__ __launch_bounds__(256) void router_kernel(
    const float* __restrict__ x, const float* __restrict__ gw,
    int* __restrict__ sel_e, float* __restrict__ sel_w, int* __restrict__ counts)
{
  __shared__ float gwt[NE * EMBED];   // transposed gate: gwt[e][i]
  __shared__ int cnt[NE];
  int tid = threadIdx.x;
  for (int idx = tid; idx < NE * EMBED; idx += 256) {
    int i = idx >> 3, e = idx & 7;
    gwt[e * EMBED + i] = gw[idx];     // gw is [EMBED][NE]
  }
  if (tid < NE) cnt[tid] = 0;
  __syncthreads();

  int lane = tid & 63, wv = tid >> 6;
  int t = blockIdx.x * 4 + wv;
  const float4* xr = (const float4*)(x + (size_t)t * EMBED);
  const float4* gt4 = (const float4*)gwt;
  float acc[NE];
  #pragma unroll
  for (int e = 0; e < NE; ++e) acc[e] = 0.f;
  #pragma unroll
  for (int c = 0; c < 4; ++c) {
    float4 xv = xr[c * 64 + lane];
    #pragma unroll
    for (int e = 0; e < NE; ++e) {
      float4 gv = gt4[e * 256 + c * 64 + lane];
      acc[e] += xv.x * gv.x + xv.y * gv.y + xv.z * gv.z + xv.w * gv.w;
    }
  }
  #pragma unroll
  for (int off = 1; off < 64; off <<= 1) {
    #pragma unroll
    for (int e = 0; e < NE; ++e) acc[e] += __shfl_xor(acc[e], off);
  }
  if (lane == 0) {
    int e0 = 0; float l0 = acc[0];
    #pragma unroll
    for (int e = 1; e < NE; ++e) if (acc[e] > l0) { l0 = acc[e]; e0 = e; }
    int e1 = -1; float l1 = -1e30f;
    #pragma unroll
    for (int e = 0; e < NE; ++e) if (e != e0 && acc[e] > l1) { l1 = acc[e]; e1 = e; }
    float w0 = 1.f / (1.f + expf(l1 - l0));   // softmax over {l0,l1}
    sel_e[2 * t] = e0;     sel_w[2 * t] = w0;
    sel_e[2 * t + 1] = e1; sel_w[2 * t + 1] = 1.f - w0;
    atomicAdd(&cnt[e0], 1); atomicAdd(&cnt[e1], 1);
  }
  __syncthreads();
  if (tid < NE && cnt[tid]) atomicAdd(&counts[tid], cnt[tid]);
}

// ---------------------------------------------------------------------------
// Assign: scatter (token, weight) into per-expert row lists + inverse map.
// Segment starts are 256-aligned (so a 256-row GEMM tile never straddles
// experts). Block 0 publishes offs; cursor is zero-based per segment.
// ---------------------------------------------------------------------------
__global__ __launch_bounds__(256) void assign_kernel(
    const int* __restrict__ sel_e, const float* __restrict__ sel_w,
    const int* __restrict__ counts, int* __restrict__ cursor,
    int* __restrict__ offs_out, int* __restrict__ rowtok,
    float* __restrict__ rowcoef, int* __restrict__ inv)
{
  int offl[NE];
  {
    int o = 0;
    #pragma unroll
    for (int e = 0; e < NE; ++e) { offl[e] = o; o += (counts[e] + 255) & ~255; }
    if (blockIdx.x == 0 && threadIdx.x == 0) {
      #pragma unroll
      for (int e = 0; e < NE; ++e) offs_out[e] = offl[e];
      offs_out[NE] = o;
    }
  }
  int t = blockIdx.x * 256 + threadIdx.x;
  int lane = threadIdx.x & 63;
  #pragma unroll
  for (int k = 0; k < 2; ++k) {
    int e = sel_e[2 * t + k];
    float w = sel_w[2 * t + k];
    for (int xch = 0; xch < NE; ++xch) {
      unsigned long long m = __ballot(e == xch);
      if (e == xch) {
        int leader = __ffsll((unsigned long long)m) - 1;
        int base = 0;
        if (lane == leader) base = atomicAdd(&cursor[xch], (int)__popcll(m));
        base = __shfl(base, leader);
        int pos = offl[xch] + base + (int)__popcll(m & ((1ull << lane) - 1));
        rowtok[pos] = t;
        rowcoef[pos] = w;
        inv[2 * t + k] = pos;
      }
    }
  }
}

// ---------------------------------------------------------------------------
// Gather: xg[row] = fp16(x[rowtok[row]]); zeros for padding rows (tok = -1).
// ---------------------------------------------------------------------------
__global__ __launch_bounds__(256) void gather_kernel(
    const float* __restrict__ x, const int* __restrict__ rowtok,
    _Float16* __restrict__ xg)
{
  int r = blockIdx.x;
  int tok = rowtok[r];
  int t4 = threadIdx.x * 4;
  _Float16* dst = xg + (size_t)r * EMBED + t4;
  if (tok >= 0) {
    float4 v = *(const float4*)(x + (size_t)tok * EMBED + t4);
    f16x4 h; h.x = (_Float16)v.x; h.y = (_Float16)v.y; h.z = (_Float16)v.z; h.w = (_Float16)v.w;
    *(f16x4*)dst = h;
  } else {
    f16x4 z = {(_Float16)0.f, (_Float16)0.f, (_Float16)0.f, (_Float16)0.f};
    *(f16x4*)dst = z;
  }
}

// ---------------------------------------------------------------------------
// Transpose+cast all three weight tensors in ONE launch.
// fp32 [E][K][N] -> fp16 [E][N][K]. 512 64x64 tiles per (matrix, expert).
// ---------------------------------------------------------------------------
__global__ __launch_bounds__(256) void transpose_all_kernel(
    const float* __restrict__ w1, const float* __restrict__ w3,
    const float* __restrict__ w2, _Float16* __restrict__ w1t,
    _Float16* __restrict__ w3t, _Float16* __restrict__ w2t)
{
  int id = blockIdx.x;            // 3 * 8 * 512
  int mat = id >> 12;             // 4096 blocks per matrix
  int rr = id & 4095;
  int e = rr >> 9, tile = rr & 511;
  const float* src; _Float16* dst; int K, N;
  if (mat == 0)      { src = w1; dst = w1t; K = EMBED; N = MLP; }
  else if (mat == 1) { src = w3; dst = w3t; K = EMBED; N = MLP; }
  else               { src = w2; dst = w2t; K = MLP;   N = EMBED; }
  int nx = K >> 6;
  int k0 = (tile % nx) * 64, n0 = (tile / nx) * 64;
  src += (size_t)e * K * N;
  dst += (size_t)e * K * N;

  __shared__ float tilebuf[64][65];
  int t = threadIdx.x;
  int r = t >> 4, c4 = (t & 15) * 4;
  #pragma unroll
  for (int i = 0; i < 4; ++i) {
    float4 v = *(const float4*)(src + (size_t)(k0 + r + 16 * i) * N + n0 + c4);
    tilebuf[r + 16 * i][c4 + 0] = v.x;
    tilebuf[r + 16 * i][c4 + 1] = v.y;
    tilebuf[r + 16 * i][c4 + 2] = v.z;
    tilebuf[r + 16 * i][c4 + 3] = v.w;
  }
  __syncthreads();
  int kk8 = (t & 7) * 8, nIdx = t >> 3;
  #pragma unroll
  for (int i = 0; i < 2; ++i) {
    int n = nIdx + 32 * i;
    f16x8 h;
    #pragma unroll
    for (int j = 0; j < 8; ++j) h[j] = (_Float16)tilebuf[kk8 + j][n];
    *(f16x8*)(dst + (size_t)(n0 + n) * K + k0 + kk8) = h;
  }
}

// ---------------------------------------------------------------------------
__device__ __forceinline__ int resolve_expert(const int* __restrict__ offs, int r0)
{
  int e = 0;
  #pragma unroll
  for (int q = 0; q < NE - 1; ++q) if (r0 >= offs[q + 1]) e = q + 1;
  return e;
}

// Tile rows x 32 f16 (64 B/row), 4 chunks of 16 B per row.
// Physical slot (row, kqp) holds logical k-quarter kql = kqp ^ ((row>>1)&3)
// (round-2-verified: 0 bank conflicts). Read: phys = quad ^ ((row>>1)&3).
__device__ __forceinline__ const _Float16* frag_addr(const _Float16* buf, int row, int quad)
{
  return buf + row * 32 + ((quad ^ ((row >> 1) & 3)) << 3);
}

// XCD-chunked bijective block swizzle (grid.x must be 72, nwg % 8 == 0).
// XCD k owns x-tiles [9k, 9k+9); within a chunk x varies fastest so the
// 9 A-tiles + current B-panel stay resident in that XCD's L2.
__device__ __forceinline__ void swz_block(int& x, int& y)
{
  int lin = blockIdx.y * 72 + blockIdx.x;   // dispatch index (x fastest)
  int xcd = lin & 7, idx = lin >> 3;
  x = xcd * 9 + idx % 9;
  y = idx / 9;
}

// ---------------------------------------------------------------------------
// GEMM1 (fused SwiGLU): h = silu(xg@w1t^T) * (xg@w3t^T) * coef, fp16 out.
// 256x128 tile, 512 threads / 8 waves (wave tile 64x64), BK=32.
// DOUBLE-buffered LDS (64 KB -> 2 blocks/CU by LDS), 2 barriers per K-iter:
//   barrier1 after counted vmcnt  -> staged buf b visible to all waves
//   barrier2 after lgkmcnt(0)     -> all frag reads of buf b retired, so the
//                                    next iter may stage into buf b^1 safely
// Counted vmcnt(4) keeps stage(k+1) in flight across both barriers.
// __launch_bounds__(512, 2): the R3 (512,4) capped unified VGPR+AGPR at
// ~128/wave and spilled the 128-reg accumulator to scratch (5.3 GB traffic,
// 7x regression). (512,2) keeps ~232 regs/wave; 2 blocks/CU still fit
// (LDS 2x64=128<=160 KB, regs 4 waves/SIMD x 232 = 928 <= 2048).
// ---------------------------------------------------------------------------
__global__ __launch_bounds__(512, 2) void gemm1_kernel(
    const _Float16* __restrict__ xg, const _Float16* __restrict__ w1t,
    const _Float16* __restrict__ w3t, const float* __restrict__ rowcoef,
    const int* __restrict__ offs, _Float16* __restrict__ hb)
{
  int bx, by; swz_block(bx, by);
  int r0 = bx * 256;
  if (r0 >= offs[NE]) return;
  int e = resolve_expert(offs, r0);
  int n0 = by * 128;
  const _Float16* B1 = w1t + (size_t)e * MLP * EMBED;
  const _Float16* B3 = w3t + (size_t)e * MLP * EMBED;

  __shared__ __align__(16) _Float16 As[2][256 * 32];    // 2 x 16 KB
  __shared__ __align__(16) _Float16 Bs1[2][128 * 32];   // 2 x 8 KB
  __shared__ __align__(16) _Float16 Bs3[2][128 * 32];   // 2 x 8 KB

  int tid = threadIdx.x, lane = tid & 63, wv = tid >> 6;  // wv 0..7
  int wm = (wv & 3) << 6, wn = (wv >> 2) << 6;            // 4 m-waves x 2 n-waves
  int l16 = lane & 15, quad = lane >> 4;

  // A: 1024 chunks, 2 per thread (c = tid, tid+512). B: 512 chunks, 1/thread.
  int rowA0 = tid >> 2, kqpA = tid & 3;
  int rowA1 = rowA0 + 128;
  int kqlA0 = kqpA ^ ((rowA0 >> 1) & 3);
  int kqlA1 = kqpA ^ ((rowA1 >> 1) & 3);
  int rowB = tid >> 2, kqpB = tid & 3;
  int kqlB = kqpB ^ ((rowB >> 1) & 3);
  size_t gA0 = (size_t)(r0 + rowA0) * EMBED + kqlA0 * 8;
  size_t gA1 = (size_t)(r0 + rowA1) * EMBED + kqlA1 * 8;
  size_t gB  = (size_t)(n0 + rowB) * EMBED + kqlB * 8;
  int lofA0 = (wv * 64) * 8;          // wave-uniform LDS bases (f16 units)
  int lofA1 = (512 + wv * 64) * 8;
  int lofB  = (wv * 64) * 8;

  f32x4 acc1[4][4], acc3[4][4];
  f32x4 z4 = {0.f, 0.f, 0.f, 0.f};
  #pragma unroll
  for (int i = 0; i < 4; ++i)
    #pragma unroll
    for (int j = 0; j < 4; ++j) { acc1[i][j] = z4; acc3[i][j] = z4; }

  auto stage = [&](int b, int kk) {
    async_copy16(xg + gA0 + kk, &As[b][lofA0]);
    async_copy16(xg + gA1 + kk, &As[b][lofA1]);
    async_copy16(B1 + gB  + kk, &Bs1[b][lofB]);
    async_copy16(B3 + gB  + kk, &Bs3[b][lofB]);
  };

  const int NIT = EMBED / 32;        // 32 iters
  stage(0, 0);
  int b = 0;
  for (int k = 0; k < NIT; ++k) {
    if (k + 1 < NIT) {
      stage(b ^ 1, (k + 1) * 32);
      asm volatile("s_waitcnt vmcnt(4)" ::: "memory");   // stage(k) drained
    } else {
      asm volatile("s_waitcnt vmcnt(0)" ::: "memory");
    }
    asm volatile("s_barrier" ::: "memory");              // buf b ready

    f16x8 af[4], b1f[4], b3f[4];
    #pragma unroll
    for (int i = 0; i < 4; ++i)
      af[i] = *(const f16x8*)frag_addr(As[b], wm + 16 * i + l16, quad);
    #pragma unroll
    for (int j = 0; j < 4; ++j) {
      b1f[j] = *(const f16x8*)frag_addr(Bs1[b], wn + 16 * j + l16, quad);
      b3f[j] = *(const f16x8*)frag_addr(Bs3[b], wn + 16 * j + l16, quad);
    }
    asm volatile("s_waitcnt lgkmcnt(0)" ::: "memory");   // frag reads retired
    asm volatile("s_barrier" ::: "memory");              // buf b free for restage

    #pragma unroll
    for (int i = 0; i < 4; ++i)
      #pragma unroll
      for (int j = 0; j < 4; ++j) {
        acc1[i][j] = __builtin_amdgcn_mfma_f32_16x16x32_f16(af[i], b1f[j], acc1[i][j], 0, 0, 0);
        acc3[i][j] = __builtin_amdgcn_mfma_f32_16x16x32_f16(af[i], b3f[j], acc3[i][j], 0, 0, 0);
      }
    b ^= 1;
  }

  // Epilogue: h = silu(g)*u*coef[row]; C/D layout col=lane&15, row=quad*4+reg.
  #pragma unroll
  for (int i = 0; i < 4; ++i) {
    int mb = r0 + wm + 16 * i + quad * 4;
    float cf[4];
    #pragma unroll
    for (int rg = 0; rg < 4; ++rg) cf[rg] = rowcoef[mb + rg];
    #pragma unroll
    for (int j = 0; j < 4; ++j) {
      int col = n0 + wn + 16 * j + l16;
      #pragma unroll
      for (int rg = 0; rg < 4; ++rg) {
        float g = acc1[i][j][rg], u = acc3[i][j][rg];
        float h = g * u * cf[rg] / (1.f + __expf(-g));
        hb[(size_t)(mb + rg) * MLP + col] = (_Float16)h;
      }
    }
  }
}

// ---------------------------------------------------------------------------
// GEMM2: hb2[row] = h[row] @ w2t^T, fp16 per-row out (no atomics; combine
// sums the 2 rows per token). 256x128 tile, same 2-barrier double-buffer,
// K=2048. LDS 48 KB; (512,2) for the same no-spill reason as gemm1.
// ---------------------------------------------------------------------------
__global__ __launch_bounds__(512, 2) void gemm2_kernel(
    const _Float16* __restrict__ hb, const _Float16* __restrict__ w2t,
    const int* __restrict__ offs, _Float16* __restrict__ hb2)
{
  int bx, by; swz_block(bx, by);
  int r0 = bx * 256;
  if (r0 >= offs[NE]) return;
  int e = resolve_expert(offs, r0);
  int n0 = by * 128;
  const _Float16* B = w2t + (size_t)e * EMBED * MLP;

  __shared__ __align__(16) _Float16 As[2][256 * 32];    // 2 x 16 KB
  __shared__ __align__(16) _Float16 Bs[2][128 * 32];    // 2 x 8 KB

  int tid = threadIdx.x, lane = tid & 63, wv = tid >> 6;
  int wm = (wv & 3) << 6, wn = (wv >> 2) << 6;
  int l16 = lane & 15, quad = lane >> 4;

  int rowA0 = tid >> 2, kqpA = tid & 3;
  int rowA1 = rowA0 + 128;
  int kqlA0 = kqpA ^ ((rowA0 >> 1) & 3);
  int kqlA1 = kqpA ^ ((rowA1 >> 1) & 3);
  int rowB = tid >> 2, kqpB = tid & 3;
  int kqlB = kqpB ^ ((rowB >> 1) & 3);
  size_t gA0 = (size_t)(r0 + rowA0) * MLP + kqlA0 * 8;
  size_t gA1 = (size_t)(r0 + rowA1) * MLP + kqlA1 * 8;
  size_t gB  = (size_t)(n0 + rowB) * MLP + kqlB * 8;
  int lofA0 = (wv * 64) * 8;
  int lofA1 = (512 + wv * 64) * 8;
  int lofB  = (wv * 64) * 8;

  f32x4 acc[4][4];
  f32x4 z4 = {0.f, 0.f, 0.f, 0.f};
  #pragma unroll
  for (int i = 0; i < 4; ++i)
    #pragma unroll
    for (int j = 0; j < 4; ++j) acc[i][j] = z4;

  auto stage = [&](int b, int kk) {
    async_copy16(hb + gA0 + kk, &As[b][lofA0]);
    async_copy16(hb + gA1 + kk, &As[b][lofA1]);
    async_copy16(B  + gB  + kk, &Bs[b][lofB]);
  };

  const int NIT = MLP / 32;          // 64 iters
  stage(0, 0);
  int b = 0;
  for (int k = 0; k < NIT; ++k) {
    if (k + 1 < NIT) {
      stage(b ^ 1, (k + 1) * 32);
      asm volatile("s_waitcnt vmcnt(3)" ::: "memory");
    } else {
      asm volatile("s_waitcnt vmcnt(0)" ::: "memory");
    }
    asm volatile("s_barrier" ::: "memory");

    f16x8 af[4], bf[4];
    #pragma unroll
    for (int i = 0; i < 4; ++i)
      af[i] = *(const f16x8*)frag_addr(As[b], wm + 16 * i + l16, quad);
    #pragma unroll
    for (int j = 0; j < 4; ++j)
      bf[j] = *(const f16x8*)frag_addr(Bs[b], wn + 16 * j + l16, quad);
    asm volatile("s_waitcnt lgkmcnt(0)" ::: "memory");
    asm volatile("s_barrier" ::: "memory");

    #pragma unroll
    for (int i = 0; i < 4; ++i)
      #pragma unroll
      for (int j = 0; j < 4; ++j)
        acc[i][j] = __builtin_amdgcn_mfma_f32_16x16x32_f16(af[i], bf[j], acc[i][j], 0, 0, 0);
    b ^= 1;
  }

  #pragma unroll
  for (int i = 0; i < 4; ++i) {
    int mb = r0 + wm + 16 * i + quad * 4;
    #pragma unroll
    for (int j = 0; j < 4; ++j) {
      int col = n0 + wn + 16 * j + l16;
      #pragma unroll
      for (int rg = 0; rg < 4; ++rg)
        hb2[(size_t)(mb + rg) * EMBED + col] = (_Float16)acc[i][j][rg];
    }
  }
}

// ---------------------------------------------------------------------------
// Combine: out[t] = hb2[inv[2t]] + hb2[inv[2t+1]] (fp32 out).
// ---------------------------------------------------------------------------
__global__ __launch_bounds__(256) void combine_kernel(
    const _Float16* __restrict__ hb2, const int* __restrict__ inv,
    float* __restrict__ out)
{
  int t = blockIdx.x;
  int d = threadIdx.x * 4;
  int p0 = inv[2 * t], p1 = inv[2 * t + 1];
  f16x4 a = *(const f16x4*)(hb2 + (size_t)p0 * EMBED + d);
  f16x4 b = *(const f16x4*)(hb2 + (size_t)p1 * EMBED + d);
  float4 r;
  r.x = (float)a.x + (float)b.x;
  r.y = (float)a.y + (float)b.y;
  r.z = (float)a.z + (float)b.z;
  r.w = (float)a.w + (float)b.w;
  *(float4*)(out + (size_t)t * EMBED + d) = r;
}

// ---------------------------------------------------------------------------
extern "C" void kernel_launch(void* const* d_in, const int* in_sizes, int n_in,
                              void* d_out, int out_size, void* d_ws, size_t ws_size,
                              hipStream_t stream)
{
  (void)in_sizes; (void)n_in; (void)ws_size; (void)out_size;
  const float* x  = (const float*)d_in[0];
  const float* gw = (const float*)d_in[1];
  const float* w1 = (const float*)d_in[2];
  const float* w2 = (const float*)d_in[3];   // NOTE: dict order is w1, w2, w3
  const float* w3 = (const float*)d_in[4];
  float* out = (float*)d_out;
  char* ws = (char*)d_ws;

  size_t o = 0;
  auto alloc = [&](size_t bytes) { size_t r = o; o = (o + bytes + 255) & ~255ULL; return r; };
  const size_t wbytes = (size_t)NE * MLP * EMBED * 2;
  _Float16* w1t = (_Float16*)(ws + alloc(wbytes));
  _Float16* w3t = (_Float16*)(ws + alloc(wbytes));
  _Float16* w2t = (_Float16*)(ws + alloc(wbytes));
  _Float16* xg  = (_Float16*)(ws + alloc((size_t)RMAX * EMBED * 2));
  _Float16* hb  = (_Float16*)(ws + alloc((size_t)RMAX * MLP * 2));
  int*   rowtok  = (int*)(ws + alloc((size_t)RMAX * 4));
  float* rowcoef = (float*)(ws + alloc((size_t)RMAX * 4));
  int*   sel_e   = (int*)(ws + alloc((size_t)2 * NTOK * 4));
  float* sel_w   = (float*)(ws + alloc((size_t)2 * NTOK * 4));
  int*   inv     = (int*)(ws + alloc((size_t)2 * NTOK * 4));
  int*   meta    = (int*)(ws + alloc(256));
  int* counts = meta;          // [8]
  int* offs   = meta + 8;      // [9]
  int* cursor = meta + 17;     // [8] (zero-based)
  // hb2 aliases xg: xg is dead after gemm1; both are RMAX*EMBED fp16.
  _Float16* hb2 = xg;

  hipMemsetAsync(meta, 0, 256, stream);
  hipMemsetAsync(rowtok, 0xFF, (size_t)RMAX * 4, stream);   // -1 = padding
  hipMemsetAsync(rowcoef, 0, (size_t)RMAX * 4, stream);

  transpose_all_kernel<<<3 * 4096, 256, 0, stream>>>(w1, w3, w2, w1t, w3t, w2t);

  router_kernel<<<NTOK / 4, 256, 0, stream>>>(x, gw, sel_e, sel_w, counts);
  assign_kernel<<<NTOK / 256, 256, 0, stream>>>(sel_e, sel_w, counts, cursor,
                                                offs, rowtok, rowcoef, inv);
  gather_kernel<<<RMAX, 256, 0, stream>>>(x, rowtok, xg);

  gemm1_kernel<<<dim3(RMAX / 256, MLP / 128), 512, 0, stream>>>(xg, w1t, w3t, rowcoef, offs, hb);
  gemm2_kernel<<<dim3(RMAX / 256, EMBED / 128), 512, 0, stream>>>(hb, w2t, offs, hb2);
  combine_kernel<<<NTOK, 256, 0, stream>>>(hb2, inv, out);
}

// Round 5
// 594.509 us; speedup vs baseline: 3.0699x; 1.0806x over previous
//
#include <hip/hip_runtime.h>

#define EMBED 1024
#define MLP   2048
#define NE    8
#define NTOK  8192                      // 4*2048 tokens
#define RMAX  (2*NTOK + NE*256)         // 18432 rows max (256-pad per expert)

typedef _Float16 f16x8 __attribute__((ext_vector_type(8)));
typedef _Float16 f16x4 __attribute__((ext_vector_type(4)));
typedef float    f32x4 __attribute__((ext_vector_type(4)));

// Async 16B global->LDS copy. LDS dest is wave-uniform base + lane*16 (HW
// constraint); we permute WHICH global chunk each lane fetches (XOR swizzle).
__device__ __forceinline__ void async_copy16(const void* g, void* l) {
  __builtin_amdgcn_global_load_lds(
      (const __attribute__((address_space(1))) unsigned int*)g,
      (__attribute__((address_space(3))) unsigned int*)l, 16, 0, 0);
}

// ---------------------------------------------------------------------------
// Router: one wave per token. logits = x[t] @ gate_w (fp32), top-2, weights =
// softmax over the two selected logits (== renormalized full softmax).
// ---------------------------------------------------------------------------
__global__ __launch_bounds__(256) void router_kernel(
    const float* __restrict__ x, const float* __restrict__ gw,
    int* __restrict__ sel_e, float* __restrict__ sel_w, int* __restrict__ counts)
{
  __shared__ float gwt[NE * EMBED];   // transposed gate: gwt[e][i]
  __shared__ int cnt[NE];
  int tid = threadIdx.x;
  for (int idx = tid; idx < NE * EMBED; idx += 256) {
    int i = idx >> 3, e = idx & 7;
    gwt[e * EMBED + i] = gw[idx];     // gw is [EMBED][NE]
  }
  if (tid < NE) cnt[tid] = 0;
  __syncthreads();

  int lane = tid & 63, wv = tid >> 6;
  int t = blockIdx.x * 4 + wv;
  const float4* xr = (const float4*)(x + (size_t)t * EMBED);
  const float4* gt4 = (const float4*)gwt;
  float acc[NE];
  #pragma unroll
  for (int e = 0; e < NE; ++e) acc[e] = 0.f;
  #pragma unroll
  for (int c = 0; c < 4; ++c) {
    float4 xv = xr[c * 64 + lane];
    #pragma unroll
    for (int e = 0; e < NE; ++e) {
      float4 gv = gt4[e * 256 + c * 64 + lane];
      acc[e] += xv.x * gv.x + xv.y * gv.y + xv.z * gv.z + xv.w * gv.w;
    }
  }
  #pragma unroll
  for (int off = 1; off < 64; off <<= 1) {
    #pragma unroll
    for (int e = 0; e < NE; ++e) acc[e] += __shfl_xor(acc[e], off);
  }
  if (lane == 0) {
    int e0 = 0; float l0 = acc[0];
    #pragma unroll
    for (int e = 1; e < NE; ++e) if (acc[e] > l0) { l0 = acc[e]; e0 = e; }
    int e1 = -1; float l1 = -1e30f;
    #pragma unroll
    for (int e = 0; e < NE; ++e) if (e != e0 && acc[e] > l1) { l1 = acc[e]; e1 = e; }
    float w0 = 1.f / (1.f + expf(l1 - l0));   // softmax over {l0,l1}
    sel_e[2 * t] = e0;     sel_w[2 * t] = w0;
    sel_e[2 * t + 1] = e1; sel_w[2 * t + 1] = 1.f - w0;
    atomicAdd(&cnt[e0], 1); atomicAdd(&cnt[e1], 1);
  }
  __syncthreads();
  if (tid < NE && cnt[tid]) atomicAdd(&counts[tid], cnt[tid]);
}

// ---------------------------------------------------------------------------
// Assign: scatter (token, weight) into per-expert row lists + inverse map.
// Segment starts are 256-aligned (so a GEMM row-tile never straddles
// experts; 128 divides 256). Block 0 publishes offs; cursor zero-based.
// ---------------------------------------------------------------------------
__global__ __launch_bounds__(256) void assign_kernel(
    const int* __restrict__ sel_e, const float* __restrict__ sel_w,
    const int* __restrict__ counts, int* __restrict__ cursor,
    int* __restrict__ offs_out, int* __restrict__ rowtok,
    float* __restrict__ rowcoef, int* __restrict__ inv)
{
  int offl[NE];
  {
    int o = 0;
    #pragma unroll
    for (int e = 0; e < NE; ++e) { offl[e] = o; o += (counts[e] + 255) & ~255; }
    if (blockIdx.x == 0 && threadIdx.x == 0) {
      #pragma unroll
      for (int e = 0; e < NE; ++e) offs_out[e] = offl[e];
      offs_out[NE] = o;
    }
  }
  int t = blockIdx.x * 256 + threadIdx.x;
  int lane = threadIdx.x & 63;
  #pragma unroll
  for (int k = 0; k < 2; ++k) {
    int e = sel_e[2 * t + k];
    float w = sel_w[2 * t + k];
    for (int xch = 0; xch < NE; ++xch) {
      unsigned long long m = __ballot(e == xch);
      if (e == xch) {
        int leader = __ffsll((unsigned long long)m) - 1;
        int base = 0;
        if (lane == leader) base = atomicAdd(&cursor[xch], (int)__popcll(m));
        base = __shfl(base, leader);
        int pos = offl[xch] + base + (int)__popcll(m & ((1ull << lane) - 1));
        rowtok[pos] = t;
        rowcoef[pos] = w;
        inv[2 * t + k] = pos;
      }
    }
  }
}

// ---------------------------------------------------------------------------
// Gather: xg[row] = fp16(x[rowtok[row]]); zeros for padding rows (tok = -1).
// ---------------------------------------------------------------------------
__global__ __launch_bounds__(256) void gather_kernel(
    const float* __restrict__ x, const int* __restrict__ rowtok,
    _Float16* __restrict__ xg)
{
  int r = blockIdx.x;
  int tok = rowtok[r];
  int t4 = threadIdx.x * 4;
  _Float16* dst = xg + (size_t)r * EMBED + t4;
  if (tok >= 0) {
    float4 v = *(const float4*)(x + (size_t)tok * EMBED + t4);
    f16x4 h; h.x = (_Float16)v.x; h.y = (_Float16)v.y; h.z = (_Float16)v.z; h.w = (_Float16)v.w;
    *(f16x4*)dst = h;
  } else {
    f16x4 z = {(_Float16)0.f, (_Float16)0.f, (_Float16)0.f, (_Float16)0.f};
    *(f16x4*)dst = z;
  }
}

// ---------------------------------------------------------------------------
// Transpose+cast all three weight tensors in ONE launch.
// fp32 [E][K][N] -> fp16 [E][N][K]. 512 64x64 tiles per (matrix, expert).
// ---------------------------------------------------------------------------
__global__ __launch_bounds__(256) void transpose_all_kernel(
    const float* __restrict__ w1, const float* __restrict__ w3,
    const float* __restrict__ w2, _Float16* __restrict__ w1t,
    _Float16* __restrict__ w3t, _Float16* __restrict__ w2t)
{
  int id = blockIdx.x;            // 3 * 8 * 512
  int mat = id >> 12;             // 4096 blocks per matrix
  int rr = id & 4095;
  int e = rr >> 9, tile = rr & 511;
  const float* src; _Float16* dst; int K, N;
  if (mat == 0)      { src = w1; dst = w1t; K = EMBED; N = MLP; }
  else if (mat == 1) { src = w3; dst = w3t; K = EMBED; N = MLP; }
  else               { src = w2; dst = w2t; K = MLP;   N = EMBED; }
  int nx = K >> 6;
  int k0 = (tile % nx) * 64, n0 = (tile / nx) * 64;
  src += (size_t)e * K * N;
  dst += (size_t)e * K * N;

  __shared__ float tilebuf[64][65];
  int t = threadIdx.x;
  int r = t >> 4, c4 = (t & 15) * 4;
  #pragma unroll
  for (int i = 0; i < 4; ++i) {
    float4 v = *(const float4*)(src + (size_t)(k0 + r + 16 * i) * N + n0 + c4);
    tilebuf[r + 16 * i][c4 + 0] = v.x;
    tilebuf[r + 16 * i][c4 + 1] = v.y;
    tilebuf[r + 16 * i][c4 + 2] = v.z;
    tilebuf[r + 16 * i][c4 + 3] = v.w;
  }
  __syncthreads();
  int kk8 = (t & 7) * 8, nIdx = t >> 3;
  #pragma unroll
  for (int i = 0; i < 2; ++i) {
    int n = nIdx + 32 * i;
    f16x8 h;
    #pragma unroll
    for (int j = 0; j < 8; ++j) h[j] = (_Float16)tilebuf[kk8 + j][n];
    *(f16x8*)(dst + (size_t)(n0 + n) * K + k0 + kk8) = h;
  }
}

// ---------------------------------------------------------------------------
__device__ __forceinline__ int resolve_expert(const int* __restrict__ offs, int r0)
{
  int e = 0;
  #pragma unroll
  for (int q = 0; q < NE - 1; ++q) if (r0 >= offs[q + 1]) e = q + 1;
  return e;
}

// Tile rows x 32 f16 (64 B/row), 4 chunks of 16 B per row.
// Physical slot (row, kqp) holds logical k-quarter kql = kqp ^ ((row>>1)&3)
// (round-2-verified: 0 bank conflicts). Read: phys = quad ^ ((row>>1)&3).
__device__ __forceinline__ const _Float16* frag_addr(const _Float16* buf, int row, int quad)
{
  return buf + row * 32 + ((quad ^ ((row >> 1) & 3)) << 3);
}

// XCD-chunked bijective block swizzle (grid.x = 144, nwg % 8 == 0).
// XCD k owns x-tiles [18k, 18k+18) (same 2304-row A footprint that measured
// FETCH 474->169 MB in R4); x varies fastest within the chunk.
__device__ __forceinline__ void swz_block(int& x, int& y)
{
  int lin = blockIdx.y * 144 + blockIdx.x;   // dispatch index (x fastest)
  int xcd = lin & 7, idx = lin >> 3;
  x = xcd * 18 + idx % 18;
  y = idx / 18;
}

// ---------------------------------------------------------------------------
// GEMM1 (fused SwiGLU): h = silu(xg@w1t^T) * (xg@w3t^T) * coef, fp16 out.
// 128x128 tile, 256 threads / 4 waves (wave tile 64x64), BK=32.
// R4 counters proved the occupancy limiter is the unified register file:
// 104 VGPR + 128 acc = 232/wave -> 2 waves/SIMD, so an 8-wave 512-thread
// block is pinned to 1 block/CU and its lockstep barriers idle the CU.
// 4-wave blocks keep the same wave count but as TWO independent blocks/CU
// (2 x 232 x 2 = 464 <= 512 regs/SIMD; LDS 2 x 72 = 144 <= 160 KB), so one
// block's vmcnt/barrier bubble is covered by the other's MFMAs (m114).
// Loop: R2-proven 3-buffer, ONE barrier/iter, counted vmcnt (stage(k+1) in
// flight across the barrier). R4's 2nd barrier + lgkmcnt(0) measured -10%.
// ---------------------------------------------------------------------------
__global__ __launch_bounds__(256, 2) void gemm1_kernel(
    const _Float16* __restrict__ xg, const _Float16* __restrict__ w1t,
    const _Float16* __restrict__ w3t, const float* __restrict__ rowcoef,
    const int* __restrict__ offs, _Float16* __restrict__ hb)
{
  int bx, by; swz_block(bx, by);
  int r0 = bx * 128;
  if (r0 >= offs[NE]) return;
  int e = resolve_expert(offs, r0);
  int n0 = by * 128;
  const _Float16* B1 = w1t + (size_t)e * MLP * EMBED;
  const _Float16* B3 = w3t + (size_t)e * MLP * EMBED;

  __shared__ __align__(16) _Float16 As[3][128 * 32];    // 3 x 8 KB
  __shared__ __align__(16) _Float16 Bs1[3][128 * 32];   // 3 x 8 KB
  __shared__ __align__(16) _Float16 Bs3[3][128 * 32];   // 3 x 8 KB

  int tid = threadIdx.x, lane = tid & 63, wv = tid >> 6;  // wv 0..3
  int wm = (wv & 1) << 6, wn = (wv >> 1) << 6;            // 2m x 2n waves
  int l16 = lane & 15, quad = lane >> 4;

  // Each tile = 512 16B-chunks; 256 threads stage 2 chunks (c = tid, tid+256).
  int row0 = tid >> 2, kqp = tid & 3;
  int row1 = row0 + 64;
  int kql0 = kqp ^ ((row0 >> 1) & 3);
  int kql1 = kqp ^ ((row1 >> 1) & 3);
  size_t gA0 = (size_t)(r0 + row0) * EMBED + kql0 * 8;
  size_t gA1 = (size_t)(r0 + row1) * EMBED + kql1 * 8;
  size_t gB0 = (size_t)(n0 + row0) * EMBED + kql0 * 8;
  size_t gB1 = (size_t)(n0 + row1) * EMBED + kql1 * 8;
  int lof0 = (wv * 64) * 8;           // wave-uniform LDS bases (f16 units)
  int lof1 = (256 + wv * 64) * 8;

  f32x4 acc1[4][4], acc3[4][4];
  f32x4 z4 = {0.f, 0.f, 0.f, 0.f};
  #pragma unroll
  for (int i = 0; i < 4; ++i)
    #pragma unroll
    for (int j = 0; j < 4; ++j) { acc1[i][j] = z4; acc3[i][j] = z4; }

  auto stage = [&](int b, int kk) {
    async_copy16(xg + gA0 + kk, &As[b][lof0]);
    async_copy16(xg + gA1 + kk, &As[b][lof1]);
    async_copy16(B1 + gB0 + kk, &Bs1[b][lof0]);
    async_copy16(B1 + gB1 + kk, &Bs1[b][lof1]);
    async_copy16(B3 + gB0 + kk, &Bs3[b][lof0]);
    async_copy16(B3 + gB1 + kk, &Bs3[b][lof1]);
  };

  const int NIT = EMBED / 32;        // 32 iters
  stage(0, 0);
  for (int k = 0; k < NIT; ++k) {
    int b = k % 3;
    if (k + 1 < NIT) {
      stage((k + 1) % 3, (k + 1) * 32);
      asm volatile("s_waitcnt vmcnt(6)" ::: "memory");   // stage(k) drained
    } else {
      asm volatile("s_waitcnt vmcnt(0)" ::: "memory");
    }
    asm volatile("s_barrier" ::: "memory");

    f16x8 af[4], b1f[4], b3f[4];
    #pragma unroll
    for (int i = 0; i < 4; ++i)
      af[i] = *(const f16x8*)frag_addr(As[b], wm + 16 * i + l16, quad);
    #pragma unroll
    for (int j = 0; j < 4; ++j) {
      b1f[j] = *(const f16x8*)frag_addr(Bs1[b], wn + 16 * j + l16, quad);
      b3f[j] = *(const f16x8*)frag_addr(Bs3[b], wn + 16 * j + l16, quad);
    }
    #pragma unroll
    for (int i = 0; i < 4; ++i)
      #pragma unroll
      for (int j = 0; j < 4; ++j) {
        acc1[i][j] = __builtin_amdgcn_mfma_f32_16x16x32_f16(af[i], b1f[j], acc1[i][j], 0, 0, 0);
        acc3[i][j] = __builtin_amdgcn_mfma_f32_16x16x32_f16(af[i], b3f[j], acc3[i][j], 0, 0, 0);
      }
  }

  // Epilogue: h = silu(g)*u*coef[row]; C/D layout col=lane&15, row=quad*4+reg.
  #pragma unroll
  for (int i = 0; i < 4; ++i) {
    int mb = r0 + wm + 16 * i + quad * 4;
    float cf[4];
    #pragma unroll
    for (int rg = 0; rg < 4; ++rg) cf[rg] = rowcoef[mb + rg];
    #pragma unroll
    for (int j = 0; j < 4; ++j) {
      int col = n0 + wn + 16 * j + l16;
      #pragma unroll
      for (int rg = 0; rg < 4; ++rg) {
        float g = acc1[i][j][rg], u = acc3[i][j][rg];
        float h = g * u * cf[rg] / (1.f + __expf(-g));
        hb[(size_t)(mb + rg) * MLP + col] = (_Float16)h;
      }
    }
  }
}

// ---------------------------------------------------------------------------
// GEMM2: hb2[row] = h[row] @ w2t^T, fp16 per-row out (no atomics; combine
// sums the 2 rows per token). 128x128 tile, 4 waves, same 3-buffer pipelined
// loop, K=2048. Regs ~104+64=168/wave -> 2 blocks/CU; LDS 48 KB.
// ---------------------------------------------------------------------------
__global__ __launch_bounds__(256, 2) void gemm2_kernel(
    const _Float16* __restrict__ hb, const _Float16* __restrict__ w2t,
    const int* __restrict__ offs, _Float16* __restrict__ hb2)
{
  int bx, by; swz_block(bx, by);
  int r0 = bx * 128;
  if (r0 >= offs[NE]) return;
  int e = resolve_expert(offs, r0);
  int n0 = by * 128;
  const _Float16* B = w2t + (size_t)e * EMBED * MLP;

  __shared__ __align__(16) _Float16 As[3][128 * 32];    // 3 x 8 KB
  __shared__ __align__(16) _Float16 Bs[3][128 * 32];    // 3 x 8 KB

  int tid = threadIdx.x, lane = tid & 63, wv = tid >> 6;
  int wm = (wv & 1) << 6, wn = (wv >> 1) << 6;
  int l16 = lane & 15, quad = lane >> 4;

  int row0 = tid >> 2, kqp = tid & 3;
  int row1 = row0 + 64;
  int kql0 = kqp ^ ((row0 >> 1) & 3);
  int kql1 = kqp ^ ((row1 >> 1) & 3);
  size_t gA0 = (size_t)(r0 + row0) * MLP + kql0 * 8;
  size_t gA1 = (size_t)(r0 + row1) * MLP + kql1 * 8;
  size_t gB0 = (size_t)(n0 + row0) * MLP + kql0 * 8;
  size_t gB1 = (size_t)(n0 + row1) * MLP + kql1 * 8;
  int lof0 = (wv * 64) * 8;
  int lof1 = (256 + wv * 64) * 8;

  f32x4 acc[4][4];
  f32x4 z4 = {0.f, 0.f, 0.f, 0.f};
  #pragma unroll
  for (int i = 0; i < 4; ++i)
    #pragma unroll
    for (int j = 0; j < 4; ++j) acc[i][j] = z4;

  auto stage = [&](int b, int kk) {
    async_copy16(hb + gA0 + kk, &As[b][lof0]);
    async_copy16(hb + gA1 + kk, &As[b][lof1]);
    async_copy16(B  + gB0 + kk, &Bs[b][lof0]);
    async_copy16(B  + gB1 + kk, &Bs[b][lof1]);
  };

  const int NIT = MLP / 32;          // 64 iters
  stage(0, 0);
  for (int k = 0; k < NIT; ++k) {
    int b = k % 3;
    if (k + 1 < NIT) {
      stage((k + 1) % 3, (k + 1) * 32);
      asm volatile("s_waitcnt vmcnt(4)" ::: "memory");
    } else {
      asm volatile("s_waitcnt vmcnt(0)" ::: "memory");
    }
    asm volatile("s_barrier" ::: "memory");

    f16x8 af[4], bf[4];
    #pragma unroll
    for (int i = 0; i < 4; ++i)
      af[i] = *(const f16x8*)frag_addr(As[b], wm + 16 * i + l16, quad);
    #pragma unroll
    for (int j = 0; j < 4; ++j)
      bf[j] = *(const f16x8*)frag_addr(Bs[b], wn + 16 * j + l16, quad);
    #pragma unroll
    for (int i = 0; i < 4; ++i)
      #pragma unroll
      for (int j = 0; j < 4; ++j)
        acc[i][j] = __builtin_amdgcn_mfma_f32_16x16x32_f16(af[i], bf[j], acc[i][j], 0, 0, 0);
  }

  #pragma unroll
  for (int i = 0; i < 4; ++i) {
    int mb = r0 + wm + 16 * i + quad * 4;
    #pragma unroll
    for (int j = 0; j < 4; ++j) {
      int col = n0 + wn + 16 * j + l16;
      #pragma unroll
      for (int rg = 0; rg < 4; ++rg)
        hb2[(size_t)(mb + rg) * EMBED + col] = (_Float16)acc[i][j][rg];
    }
  }
}

// ---------------------------------------------------------------------------
// Combine: out[t] = hb2[inv[2t]] + hb2[inv[2t+1]] (fp32 out).
// ---------------------------------------------------------------------------
__global__ __launch_bounds__(256) void combine_kernel(
    const _Float16* __restrict__ hb2, const int* __restrict__ inv,
    float* __restrict__ out)
{
  int t = blockIdx.x;
  int d = threadIdx.x * 4;
  int p0 = inv[2 * t], p1 = inv[2 * t + 1];
  f16x4 a = *(const f16x4*)(hb2 + (size_t)p0 * EMBED + d);
  f16x4 b = *(const f16x4*)(hb2 + (size_t)p1 * EMBED + d);
  float4 r;
  r.x = (float)a.x + (float)b.x;
  r.y = (float)a.y + (float)b.y;
  r.z = (float)a.z + (float)b.z;
  r.w = (float)a.w + (float)b.w;
  *(float4*)(out + (size_t)t * EMBED + d) = r;
}

// ---------------------------------------------------------------------------
extern "C" void kernel_launch(void* const* d_in, const int* in_sizes, int n_in,
                              void* d_out, int out_size, void* d_ws, size_t ws_size,
                              hipStream_t stream)
{
  (void)in_sizes; (void)n_in; (void)ws_size; (void)out_size;
  const float* x  = (const float*)d_in[0];
  const float* gw = (const float*)d_in[1];
  const float* w1 = (const float*)d_in[2];
  const float* w2 = (const float*)d_in[3];   // NOTE: dict order is w1, w2, w3
  const float* w3 = (const float*)d_in[4];
  float* out = (float*)d_out;
  char* ws = (char*)d_ws;

  size_t o = 0;
  auto alloc = [&](size_t bytes) { size_t r = o; o = (o + bytes + 255) & ~255ULL; return r; };
  const size_t wbytes = (size_t)NE * MLP * EMBED * 2;
  _Float16* w1t = (_Float16*)(ws + alloc(wbytes));
  _Float16* w3t = (_Float16*)(ws + alloc(wbytes));
  _Float16* w2t = (_Float16*)(ws + alloc(wbytes));
  _Float16* xg  = (_Float16*)(ws + alloc((size_t)RMAX * EMBED * 2));
  _Float16* hb  = (_Float16*)(ws + alloc((size_t)RMAX * MLP * 2));
  int*   rowtok  = (int*)(ws + alloc((size_t)RMAX * 4));
  float* rowcoef = (float*)(ws + alloc((size_t)RMAX * 4));
  int*   sel_e   = (int*)(ws + alloc((size_t)2 * NTOK * 4));
  float* sel_w   = (float*)(ws + alloc((size_t)2 * NTOK * 4));
  int*   inv     = (int*)(ws + alloc((size_t)2 * NTOK * 4));
  int*   meta    = (int*)(ws + alloc(256));
  int* counts = meta;          // [8]
  int* offs   = meta + 8;      // [9]
  int* cursor = meta + 17;     // [8] (zero-based)
  // hb2 aliases xg: xg is dead after gemm1; both are RMAX*EMBED fp16.
  _Float16* hb2 = xg;

  hipMemsetAsync(meta, 0, 256, stream);
  hipMemsetAsync(rowtok, 0xFF, (size_t)RMAX * 4, stream);   // -1 = padding
  hipMemsetAsync(rowcoef, 0, (size_t)RMAX * 4, stream);

  transpose_all_kernel<<<3 * 4096, 256, 0, stream>>>(w1, w3, w2, w1t, w3t, w2t);

  router_kernel<<<NTOK / 4, 256, 0, stream>>>(x, gw, sel_e, sel_w, counts);
  assign_kernel<<<NTOK / 256, 256, 0, stream>>>(sel_e, sel_w, counts, cursor,
                                                offs, rowtok, rowcoef, inv);
  gather_kernel<<<RMAX, 256, 0, stream>>>(x, rowtok, xg);

  gemm1_kernel<<<dim3(RMAX / 128, MLP / 128), 256, 0, stream>>>(xg, w1t, w3t, rowcoef, offs, hb);
  gemm2_kernel<<<dim3(RMAX / 128, EMBED / 128), 256, 0, stream>>>(hb, w2t, offs, hb2);
  combine_kernel<<<NTOK, 256, 0, stream>>>(hb2, inv, out);
}